// Round 7
// baseline (1380.056 us; speedup 1.0000x reference)
//
#include <hip/hip_runtime.h>

#define N_NODES 100000
#define N_EDGES 1600000
#define D 128
#define NBS 98           // scan blocks: ceil(100000/1024)
#define NCH 16           // feature chunks (8 dims each)
#define CHW 8            // dims per chunk
#define MAXE 2048        // LDS edge-stage capacity per 64-node block (mean 1024)

typedef __attribute__((ext_vector_type(8))) short bf16x8;
typedef __attribute__((ext_vector_type(4))) float f32x4;
typedef __attribute__((ext_vector_type(4))) unsigned int u32x4;
typedef __attribute__((ext_vector_type(2))) unsigned int u32x2;

union U16x8 { u32x4 u; bf16x8 b; };

__device__ __forceinline__ unsigned int bf16_rne_hi(float x) {
    unsigned int u = __float_as_uint(x);
    unsigned int r = u + 0x7fffu + ((u >> 16) & 1u);
    return r & 0xffff0000u;
}
__device__ __forceinline__ unsigned int pack_hilo(float x) {
    unsigned int hb = bf16_rne_hi(x);
    float hf = __uint_as_float(hb);
    unsigned int lb = bf16_rne_hi(x - hf);
    return hb | (lb >> 16);
}
__device__ __forceinline__ float unpack_val(unsigned int p) {
    return __uint_as_float(p & 0xffff0000u) + __uint_as_float(p << 16);
}

// ---------------- CSR build ----------------

__global__ __launch_bounds__(256) void hist_kernel(const int* __restrict__ dst,
                                                   int* __restrict__ cnt, int n) {
    int i = blockIdx.x * blockDim.x + threadIdx.x;
    if (i < n) atomicAdd(&cnt[dst[i]], 1);
}

__global__ __launch_bounds__(256) void scan_reduce(const int* __restrict__ cnt,
                                                   int* __restrict__ bsum, int n) {
    __shared__ int s[4];
    int b = blockIdx.x, t = threadIdx.x;
    int base = b * 1024;
    int v = 0;
    for (int q = 0; q < 4; ++q) {
        int i = base + q * 256 + t;
        if (i < n) v += cnt[i];
    }
    for (int off = 32; off > 0; off >>= 1) v += __shfl_down(v, off, 64);
    if ((t & 63) == 0) s[t >> 6] = v;
    __syncthreads();
    if (t == 0) bsum[b] = s[0] + s[1] + s[2] + s[3];
}

__global__ __launch_bounds__(128) void scan_partials(const int* __restrict__ bsum,
                                                     int* __restrict__ bpre) {
    __shared__ int s[128];
    int t = threadIdx.x;
    int v = (t < NBS) ? bsum[t] : 0;
    s[t] = v;
    __syncthreads();
    for (int off = 1; off < 128; off <<= 1) {
        int u = (t >= off) ? s[t - off] : 0;
        __syncthreads();
        s[t] += u;
        __syncthreads();
    }
    if (t < NBS) bpre[t] = s[t] - v;
}

__global__ __launch_bounds__(1024) void scan_write(const int* __restrict__ cnt,
                                                   const int* __restrict__ bpre,
                                                   int* __restrict__ row_ptr, int n) {
    __shared__ int s[1024];
    int b = blockIdx.x, t = threadIdx.x;
    int i = b * 1024 + t;
    int c = (i < n) ? cnt[i] : 0;
    s[t] = c;
    __syncthreads();
    for (int off = 1; off < 1024; off <<= 1) {
        int u = (t >= off) ? s[t - off] : 0;
        __syncthreads();
        s[t] += u;
        __syncthreads();
    }
    if (i < n) row_ptr[i] = bpre[b] + s[t] - c;
    if (b == 0 && t == 0) row_ptr[n] = N_EDGES;
}

__global__ __launch_bounds__(256) void scatter_kernel(const int* __restrict__ src,
                                                      const int* __restrict__ dst,
                                                      const int* __restrict__ row_ptr,
                                                      int* __restrict__ cursor,
                                                      int* __restrict__ sorted_src, int n) {
    int i = blockIdx.x * blockDim.x + threadIdx.x;
    if (i < n) {
        int d = dst[i];
        int p = atomicAdd(&cursor[d], 1);
        sorted_src[row_ptr[d] + p] = src[i];
    }
}

// ---------------- splits ----------------

// W -> o-major bf16 hi/lo planes: whi[o][k] for k-concat(Wl,Wr)
__global__ __launch_bounds__(256) void split_w(const float* __restrict__ Wl,
                                               const float* __restrict__ Wr,
                                               unsigned short* __restrict__ whi,
                                               unsigned short* __restrict__ wlo) {
    int i = blockIdx.x * 256 + threadIdx.x;          // 128 o x 256 k
    if (i >= 128 * 256) return;
    int o = i >> 8, k = i & 255;
    float v = (k < 128) ? Wl[o * 128 + k] : Wr[o * 128 + (k - 128)];
    unsigned int hb = bf16_rne_hi(v);
    whi[i] = (unsigned short)(hb >> 16);
    wlo[i] = (unsigned short)(bf16_rne_hi(v - __uint_as_float(hb)) >> 16);
}

// x fp32 row-major -> chunk-transposed packed Hp_t[c][n][8]
__global__ __launch_bounds__(256) void split_x_t(const float* __restrict__ x,
                                                 unsigned int* __restrict__ Hpt) {
    int i = blockIdx.x * 256 + threadIdx.x;          // 100K n x 16 c
    if (i >= N_NODES * NCH) return;
    int n = i >> 4, c = i & 15;
    float4 v0 = *reinterpret_cast<const float4*>(x + (size_t)n * D + c * CHW);
    float4 v1 = *reinterpret_cast<const float4*>(x + (size_t)n * D + c * CHW + 4);
    u32x4 p0, p1;
    p0.x = pack_hilo(v0.x); p0.y = pack_hilo(v0.y);
    p0.z = pack_hilo(v0.z); p0.w = pack_hilo(v0.w);
    p1.x = pack_hilo(v1.x); p1.y = pack_hilo(v1.y);
    p1.z = pack_hilo(v1.z); p1.w = pack_hilo(v1.w);
    unsigned int* o = Hpt + ((size_t)c * N_NODES + n) * CHW;
    *reinterpret_cast<u32x4*>(o) = p0;
    *reinterpret_cast<u32x4*>(o + 4) = p1;
}

// x fp32 -> row-major packed (fallback path)
__global__ __launch_bounds__(256) void split_x(const float* __restrict__ x,
                                               unsigned int* __restrict__ Hp) {
    int i = blockIdx.x * 256 + threadIdx.x;
    if (i >= N_NODES * 32) return;
    float4 v = reinterpret_cast<const float4*>(x)[i];
    u32x4 p;
    p.x = pack_hilo(v.x); p.y = pack_hilo(v.y);
    p.z = pack_hilo(v.z); p.w = pack_hilo(v.w);
    *reinterpret_cast<u32x4*>(Hp + (size_t)i * 4) = p;
}

// ---------------- chunked aggregation (L2-resident gathers) ----------------
// Block = 64 nodes, 512 thr / 8 waves. Wave lanes = 8 nodes x 8 dims.
// Chunks outer: per chunk the gather working set is 3.2 MB (fits XCD L2).

__global__ __launch_bounds__(512) void aggregate_chunked(
        const unsigned int* __restrict__ Hpt,
        const int* __restrict__ row_ptr,
        const int* __restrict__ sorted_src,
        unsigned int* __restrict__ Apt) {
    __shared__ int ebeg[65];
    __shared__ int eidx[MAXE];
    int tid = threadIdx.x;
    int node0 = blockIdx.x * 64;

    if (tid < 65) ebeg[tid] = row_ptr[min(node0 + tid, N_NODES)];
    __syncthreads();
    int base = ebeg[0];
    int total = ebeg[64] - base;
    bool ov = total > MAXE;
    if (!ov)
        for (int i = tid; i < total; i += 512) eidx[i] = sorted_src[base + i];
    __syncthreads();

    int w = tid >> 6, lane = tid & 63;
    int nl = w * 8 + (lane >> 3);      // node-local 0..63
    int d = lane & 7;                  // dim within chunk
    int node = node0 + nl;
    bool valid = node < N_NODES;
    int jb = ebeg[nl] - base;
    int je = ebeg[nl + 1] - base;
    float inv = 1.0f / (float)max(je - jb, 1);

    for (int c = 0; c < NCH; ++c) {
        const unsigned int* cb = Hpt + (size_t)c * N_NODES * CHW;
        float acc = 0.f;
        int j = jb;
        if (!ov) {
            for (; j + 7 < je; j += 8) {
                int s0 = eidx[j + 0], s1 = eidx[j + 1], s2 = eidx[j + 2], s3 = eidx[j + 3];
                int s4 = eidx[j + 4], s5 = eidx[j + 5], s6 = eidx[j + 6], s7 = eidx[j + 7];
                unsigned int a0 = cb[(size_t)s0 * CHW + d];
                unsigned int a1 = cb[(size_t)s1 * CHW + d];
                unsigned int a2 = cb[(size_t)s2 * CHW + d];
                unsigned int a3 = cb[(size_t)s3 * CHW + d];
                unsigned int a4 = cb[(size_t)s4 * CHW + d];
                unsigned int a5 = cb[(size_t)s5 * CHW + d];
                unsigned int a6 = cb[(size_t)s6 * CHW + d];
                unsigned int a7 = cb[(size_t)s7 * CHW + d];
                acc += (unpack_val(a0) + unpack_val(a1)) + (unpack_val(a2) + unpack_val(a3))
                     + ((unpack_val(a4) + unpack_val(a5)) + (unpack_val(a6) + unpack_val(a7)));
            }
            for (; j < je; ++j) {
                unsigned int a = cb[(size_t)eidx[j] * CHW + d];
                acc += unpack_val(a);
            }
        } else {
            for (; j < je; ++j) {
                int s = sorted_src[base + j];
                acc += unpack_val(cb[(size_t)s * CHW + d]);
            }
        }
        if (valid)
            Apt[(size_t)c * N_NODES * CHW + (size_t)node * CHW + d] = pack_hilo(acc * inv);
    }
}

// ---------------- row-major aggregation (fallback) ----------------

__global__ __launch_bounds__(256) void aggregate_packed(const unsigned int* __restrict__ Hp,
                                                        const int* __restrict__ row_ptr,
                                                        const int* __restrict__ sorted_src,
                                                        unsigned int* __restrict__ Ap) {
    int wid = (blockIdx.x * blockDim.x + threadIdx.x) >> 6;
    int lane = threadIdx.x & 63;
    if (wid >= N_NODES) return;
    int beg = row_ptr[wid], end = row_ptr[wid + 1];
    int deg = end - beg;
    float a0 = 0.f, a1 = 0.f;
    int j = beg;
    for (; j + 7 < end; j += 8) {
        int s0 = sorted_src[j + 0], s1 = sorted_src[j + 1];
        int s2 = sorted_src[j + 2], s3 = sorted_src[j + 3];
        int s4 = sorted_src[j + 4], s5 = sorted_src[j + 5];
        int s6 = sorted_src[j + 6], s7 = sorted_src[j + 7];
        u32x2 p0 = *reinterpret_cast<const u32x2*>(Hp + (size_t)s0 * D + lane * 2);
        u32x2 p1 = *reinterpret_cast<const u32x2*>(Hp + (size_t)s1 * D + lane * 2);
        u32x2 p2 = *reinterpret_cast<const u32x2*>(Hp + (size_t)s2 * D + lane * 2);
        u32x2 p3 = *reinterpret_cast<const u32x2*>(Hp + (size_t)s3 * D + lane * 2);
        u32x2 p4 = *reinterpret_cast<const u32x2*>(Hp + (size_t)s4 * D + lane * 2);
        u32x2 p5 = *reinterpret_cast<const u32x2*>(Hp + (size_t)s5 * D + lane * 2);
        u32x2 p6 = *reinterpret_cast<const u32x2*>(Hp + (size_t)s6 * D + lane * 2);
        u32x2 p7 = *reinterpret_cast<const u32x2*>(Hp + (size_t)s7 * D + lane * 2);
        a0 += unpack_val(p0.x) + unpack_val(p1.x) + unpack_val(p2.x) + unpack_val(p3.x)
            + unpack_val(p4.x) + unpack_val(p5.x) + unpack_val(p6.x) + unpack_val(p7.x);
        a1 += unpack_val(p0.y) + unpack_val(p1.y) + unpack_val(p2.y) + unpack_val(p3.y)
            + unpack_val(p4.y) + unpack_val(p5.y) + unpack_val(p6.y) + unpack_val(p7.y);
    }
    for (; j < end; ++j) {
        int s = sorted_src[j];
        u32x2 p = *reinterpret_cast<const u32x2*>(Hp + (size_t)s * D + lane * 2);
        a0 += unpack_val(p.x);
        a1 += unpack_val(p.y);
    }
    float inv = 1.0f / (float)max(deg, 1);
    u32x2 o;
    o.x = pack_hilo(a0 * inv);
    o.y = pack_hilo(a1 * inv);
    *reinterpret_cast<u32x2*>(Ap + (size_t)wid * D + lane * 2) = o;
}

// ---------------- MFMA dual GEMM, W in LDS; A from chunk-transposed buffers ----
// TR=1: A operands read from [chunk][node][8] layout; pack_out writes same layout.
// TR=0: row-major packed layout (fallback; Hp may alias outp per-row safely).

template<int TR>
__global__ __launch_bounds__(512, 2) void sage_gemm_mfma(
        const unsigned int* __restrict__ Hp,
        const unsigned int* __restrict__ Ap,
        const unsigned short* __restrict__ WHI,  // [128 o][256 k] bf16 hi
        const unsigned short* __restrict__ WLO,
        const float* __restrict__ bl,
        void* __restrict__ outp,
        int relu, int pack_out) {
    __shared__ short WH[32768];   // 64 KB
    __shared__ short WLl[32768];  // 64 KB
    int tid = threadIdx.x;

    for (int i = tid; i < 4096; i += 512) {
        int o = i >> 5, kg = i & 31;
        int sk = (kg * 8) ^ ((o & 7) << 3);
        *reinterpret_cast<bf16x8*>(&WH[o * 256 + sk]) =
            *reinterpret_cast<const bf16x8*>(WHI + o * 256 + kg * 8);
        *reinterpret_cast<bf16x8*>(&WLl[o * 256 + sk]) =
            *reinterpret_cast<const bf16x8*>(WLO + o * 256 + kg * 8);
    }
    __syncthreads();

    int w = tid >> 6, l = tid & 63;
    int lr = l & 15, lg = l >> 4;
    int sw = (lr & 7) << 3;
    int mt0 = blockIdx.x * 256 + w * 32;
    int mt1 = mt0 + 16;
    int r0 = min(mt0 + lr, N_NODES - 1);
    int r1 = min(mt1 + lr, N_NODES - 1);

    const size_t STEP = (size_t)4 * N_NODES * CHW;   // 4 chunks ahead per kk
    const unsigned int* a0A;
    const unsigned int* a0H;
    const unsigned int* a1A;
    const unsigned int* a1H;
    if (TR) {
        a0A = Ap + ((size_t)lg * N_NODES + r0) * CHW;
        a0H = Hp + ((size_t)lg * N_NODES + r0) * CHW;
        a1A = Ap + ((size_t)lg * N_NODES + r1) * CHW;
        a1H = Hp + ((size_t)lg * N_NODES + r1) * CHW;
    } else {
        a0A = Ap + (size_t)r0 * D + lg * 8;
        a0H = Hp + (size_t)r0 * D + lg * 8;
        a1A = Ap + (size_t)r1 * D + lg * 8;
        a1H = Hp + (size_t)r1 * D + lg * 8;
    }

    f32x4 acc0[8], acc1[8];
    #pragma unroll
    for (int nt = 0; nt < 8; ++nt) { acc0[nt] = (f32x4)0.f; acc1[nt] = (f32x4)0.f; }

    u32x4 p00 = *reinterpret_cast<const u32x4*>(a0A);
    u32x4 p01 = *reinterpret_cast<const u32x4*>(a0A + 4);
    u32x4 p10 = *reinterpret_cast<const u32x4*>(a1A);
    u32x4 p11 = *reinterpret_cast<const u32x4*>(a1A + 4);

    #pragma unroll
    for (int kk = 0; kk < 8; ++kk) {
        U16x8 h0, l0, h1, l1;
        h0.u.x = (p00.x >> 16) | (p00.y & 0xffff0000u);
        l0.u.x = (p00.x & 0xffffu) | (p00.y << 16);
        h0.u.y = (p00.z >> 16) | (p00.w & 0xffff0000u);
        l0.u.y = (p00.z & 0xffffu) | (p00.w << 16);
        h0.u.z = (p01.x >> 16) | (p01.y & 0xffff0000u);
        l0.u.z = (p01.x & 0xffffu) | (p01.y << 16);
        h0.u.w = (p01.z >> 16) | (p01.w & 0xffff0000u);
        l0.u.w = (p01.z & 0xffffu) | (p01.w << 16);
        h1.u.x = (p10.x >> 16) | (p10.y & 0xffff0000u);
        l1.u.x = (p10.x & 0xffffu) | (p10.y << 16);
        h1.u.y = (p10.z >> 16) | (p10.w & 0xffff0000u);
        l1.u.y = (p10.z & 0xffffu) | (p10.w << 16);
        h1.u.z = (p11.x >> 16) | (p11.y & 0xffff0000u);
        l1.u.z = (p11.x & 0xffffu) | (p11.y << 16);
        h1.u.w = (p11.z >> 16) | (p11.w & 0xffff0000u);
        l1.u.w = (p11.z & 0xffffu) | (p11.w << 16);
        bf16x8 a0h = h0.b, a0l = l0.b, a1h = h1.b, a1l = l1.b;

        if (kk < 7) {
            int kn = kk + 1;
            const unsigned int *s0, *s1;
            if (TR) {
                s0 = (kn < 4) ? (a0A + (size_t)kn * STEP) : (a0H + (size_t)(kn - 4) * STEP);
                s1 = (kn < 4) ? (a1A + (size_t)kn * STEP) : (a1H + (size_t)(kn - 4) * STEP);
            } else {
                s0 = (kn < 4) ? (a0A + kn * 32) : (a0H + (kn - 4) * 32);
                s1 = (kn < 4) ? (a1A + kn * 32) : (a1H + (kn - 4) * 32);
            }
            p00 = *reinterpret_cast<const u32x4*>(s0);
            p01 = *reinterpret_cast<const u32x4*>(s0 + 4);
            p10 = *reinterpret_cast<const u32x4*>(s1);
            p11 = *reinterpret_cast<const u32x4*>(s1 + 4);
        }

        int ka = (kk * 32 + lg * 8) ^ sw;
        #pragma unroll
        for (int nt = 0; nt < 8; ++nt) {
            int base = nt * 4096 + lr * 256 + ka;
            bf16x8 bh = *reinterpret_cast<const bf16x8*>(WH + base);
            bf16x8 bl_ = *reinterpret_cast<const bf16x8*>(WLl + base);
            acc0[nt] = __builtin_amdgcn_mfma_f32_16x16x32_bf16(a0h, bh, acc0[nt], 0, 0, 0);
            acc0[nt] = __builtin_amdgcn_mfma_f32_16x16x32_bf16(a0l, bh, acc0[nt], 0, 0, 0);
            acc0[nt] = __builtin_amdgcn_mfma_f32_16x16x32_bf16(a0h, bl_, acc0[nt], 0, 0, 0);
            acc1[nt] = __builtin_amdgcn_mfma_f32_16x16x32_bf16(a1h, bh, acc1[nt], 0, 0, 0);
            acc1[nt] = __builtin_amdgcn_mfma_f32_16x16x32_bf16(a1l, bh, acc1[nt], 0, 0, 0);
            acc1[nt] = __builtin_amdgcn_mfma_f32_16x16x32_bf16(a1h, bl_, acc1[nt], 0, 0, 0);
        }
    }

    // epilogue: D layout col=lane&15, row=(lane>>4)*4+reg [m89-verified]
    #pragma unroll
    for (int nt = 0; nt < 8; ++nt) {
        int col = nt * 16 + lr;
        float bv = bl[col];
        #pragma unroll
        for (int ri = 0; ri < 4; ++ri) {
            int n0 = mt0 + lg * 4 + ri;
            if (n0 < N_NODES) {
                float v = acc0[nt][ri] + bv;
                if (relu) v = fmaxf(v, 0.f);
                if (pack_out) {
                    if (TR)
                        ((unsigned int*)outp)[((size_t)(col >> 3) * N_NODES + n0) * CHW + (col & 7)] = pack_hilo(v);
                    else
                        ((unsigned int*)outp)[(size_t)n0 * D + col] = pack_hilo(v);
                } else
                    ((float*)outp)[(size_t)n0 * D + col] = v;
            }
            int n1 = mt1 + lg * 4 + ri;
            if (n1 < N_NODES) {
                float v = acc1[nt][ri] + bv;
                if (relu) v = fmaxf(v, 0.f);
                if (pack_out) {
                    if (TR)
                        ((unsigned int*)outp)[((size_t)(col >> 3) * N_NODES + n1) * CHW + (col & 7)] = pack_hilo(v);
                    else
                        ((unsigned int*)outp)[(size_t)n1 * D + col] = pack_hilo(v);
                } else
                    ((float*)outp)[(size_t)n1 * D + col] = v;
            }
        }
    }
}

// ---------------- launch ----------------

extern "C" void kernel_launch(void* const* d_in, const int* in_sizes, int n_in,
                              void* d_out, int out_size, void* d_ws, size_t ws_size,
                              hipStream_t stream) {
    const float* x   = (const float*)d_in[0];
    const int*   src = (const int*)d_in[1];
    const int*   dst = (const int*)d_in[2];
    const float* Wl0 = (const float*)d_in[3];
    const float* bl0 = (const float*)d_in[4];
    const float* Wr0 = (const float*)d_in[5];
    const float* Wl1 = (const float*)d_in[6];
    const float* bl1 = (const float*)d_in[7];
    const float* Wr1 = (const float*)d_in[8];
    const float* Wl2 = (const float*)d_in[9];
    const float* bl2 = (const float*)d_in[10];
    const float* Wr2 = (const float*)d_in[11];

    int* cnt        = (int*)d_ws;                        // 100032 ints (reused as cursor)
    int* row_ptr    = cnt + 100032;                      // 100001 ints
    int* sorted_src = row_ptr + 100032;                  // 1.6M ints (ends at 7200256 B)
    unsigned short* W0h = (unsigned short*)((char*)d_ws + 7200256);  // 6 x 64 KB planes
    unsigned short* W0l = W0h + 32768;
    unsigned short* W1h = W0l + 32768;
    unsigned short* W1l = W1h + 32768;
    unsigned short* W2h = W1l + 32768;
    unsigned short* W2l = W2h + 32768;
    int* bsum = (int*)W0h;   // scan temps alias W planes (written later)
    int* bpre = bsum + 128;

    const int EB = (N_EDGES + 255) / 256;      // 6250
    const int GB = (N_NODES + 255) / 256;      // 391
    const int WB = (128 * 256 + 255) / 256;    // 128

    // CSR build (shared by both paths)
    hipMemsetAsync(cnt, 0, N_NODES * sizeof(int), stream);
    hist_kernel<<<EB, 256, 0, stream>>>(dst, cnt, N_EDGES);
    scan_reduce<<<NBS, 256, 0, stream>>>(cnt, bsum, N_NODES);
    scan_partials<<<1, 128, 0, stream>>>(bsum, bpre);
    scan_write<<<NBS, 1024, 0, stream>>>(cnt, bpre, row_ptr, N_NODES);
    hipMemsetAsync(cnt, 0, N_NODES * sizeof(int), stream);
    scatter_kernel<<<EB, 256, 0, stream>>>(src, dst, row_ptr, cnt, sorted_src, N_EDGES);

    split_w<<<WB, 256, 0, stream>>>(Wl0, Wr0, W0h, W0l);
    split_w<<<WB, 256, 0, stream>>>(Wl1, Wr1, W1h, W1l);
    split_w<<<WB, 256, 0, stream>>>(Wl2, Wr2, W2h, W2l);

    if (ws_size >= 110000000ull) {
        // chunk-transposed path: Hp_t and Ap_t both in ws (no aliasing with d_out)
        unsigned int* Hpt = (unsigned int*)((char*)d_ws + 7593472);   // 51.2 MB
        unsigned int* Apt = (unsigned int*)((char*)d_ws + 58793472);  // 51.2 MB
        float* outf = (float*)d_out;
        const int SB = (N_NODES * NCH + 255) / 256;   // 6250
        const int AGB = (N_NODES + 63) / 64;          // 1563

        split_x_t<<<SB, 256, 0, stream>>>(x, Hpt);

        aggregate_chunked<<<AGB, 512, 0, stream>>>(Hpt, row_ptr, sorted_src, Apt);
        sage_gemm_mfma<1><<<GB, 512, 0, stream>>>(Hpt, Apt, W0h, W0l, bl0, Hpt, 1, 1);
        aggregate_chunked<<<AGB, 512, 0, stream>>>(Hpt, row_ptr, sorted_src, Apt);
        sage_gemm_mfma<1><<<GB, 512, 0, stream>>>(Hpt, Apt, W1h, W1l, bl1, Hpt, 1, 1);
        aggregate_chunked<<<AGB, 512, 0, stream>>>(Hpt, row_ptr, sorted_src, Apt);
        sage_gemm_mfma<1><<<GB, 512, 0, stream>>>(Hpt, Apt, W2h, W2l, bl2, outf, 0, 0);
    } else {
        // fallback: proven R6 row-major path (Hp lives in d_out, per-row in-place)
        unsigned int* Ap = (unsigned int*)((char*)d_ws + 7593472);
        unsigned int* Hp = (unsigned int*)d_out;
        float* outf = (float*)d_out;
        const int SB = (N_NODES * 32 + 255) / 256;
        const int AB = (N_NODES * 64 + 255) / 256;

        split_x<<<SB, 256, 0, stream>>>(x, Hp);

        aggregate_packed<<<AB, 256, 0, stream>>>(Hp, row_ptr, sorted_src, Ap);
        sage_gemm_mfma<0><<<GB, 512, 0, stream>>>(Hp, Ap, W0h, W0l, bl0, Hp, 1, 1);
        aggregate_packed<<<AB, 256, 0, stream>>>(Hp, row_ptr, sorted_src, Ap);
        sage_gemm_mfma<0><<<GB, 512, 0, stream>>>(Hp, Ap, W1h, W1l, bl1, Hp, 1, 1);
        aggregate_packed<<<AB, 256, 0, stream>>>(Hp, row_ptr, sorted_src, Ap);
        sage_gemm_mfma<0><<<GB, 512, 0, stream>>>(Hp, Ap, W2h, W2l, bl2, outf, 0, 0);
    }
}

// Round 8
// 683.345 us; speedup vs baseline: 2.0196x; 2.0196x over previous
//
#include <hip/hip_runtime.h>
#include <hip/hip_fp16.h>

#define N_NODES 100000
#define N_EDGES 1600000
#define D 128
#define NBS 98           // scan blocks: ceil(100000/1024)

typedef __attribute__((ext_vector_type(8))) short bf16x8;
typedef __attribute__((ext_vector_type(4))) float f32x4;
typedef __attribute__((ext_vector_type(4))) unsigned int u32x4;
typedef __attribute__((ext_vector_type(2))) unsigned int u32x2;

union U16x8 { u32x4 u; bf16x8 b; };

__device__ __forceinline__ unsigned int bf16_rne_hi(float x) {
    unsigned int u = __float_as_uint(x);
    unsigned int r = u + 0x7fffu + ((u >> 16) & 1u);
    return r & 0xffff0000u;
}
__device__ __forceinline__ unsigned int pack_hilo(float x) {
    unsigned int hb = bf16_rne_hi(x);
    float hf = __uint_as_float(hb);
    unsigned int lb = bf16_rne_hi(x - hf);
    return hb | (lb >> 16);
}

// ---------------- CSR build ----------------

__global__ __launch_bounds__(256) void hist_kernel(const int* __restrict__ dst,
                                                   int* __restrict__ cnt, int n) {
    int i = blockIdx.x * blockDim.x + threadIdx.x;
    if (i < n) atomicAdd(&cnt[dst[i]], 1);
}

__global__ __launch_bounds__(256) void scan_reduce(const int* __restrict__ cnt,
                                                   int* __restrict__ bsum, int n) {
    __shared__ int s[4];
    int b = blockIdx.x, t = threadIdx.x;
    int base = b * 1024;
    int v = 0;
    for (int q = 0; q < 4; ++q) {
        int i = base + q * 256 + t;
        if (i < n) v += cnt[i];
    }
    for (int off = 32; off > 0; off >>= 1) v += __shfl_down(v, off, 64);
    if ((t & 63) == 0) s[t >> 6] = v;
    __syncthreads();
    if (t == 0) bsum[b] = s[0] + s[1] + s[2] + s[3];
}

__global__ __launch_bounds__(128) void scan_partials(const int* __restrict__ bsum,
                                                     int* __restrict__ bpre) {
    __shared__ int s[128];
    int t = threadIdx.x;
    int v = (t < NBS) ? bsum[t] : 0;
    s[t] = v;
    __syncthreads();
    for (int off = 1; off < 128; off <<= 1) {
        int u = (t >= off) ? s[t - off] : 0;
        __syncthreads();
        s[t] += u;
        __syncthreads();
    }
    if (t < NBS) bpre[t] = s[t] - v;
}

__global__ __launch_bounds__(1024) void scan_write(const int* __restrict__ cnt,
                                                   const int* __restrict__ bpre,
                                                   int* __restrict__ row_ptr, int n) {
    __shared__ int s[1024];
    int b = blockIdx.x, t = threadIdx.x;
    int i = b * 1024 + t;
    int c = (i < n) ? cnt[i] : 0;
    s[t] = c;
    __syncthreads();
    for (int off = 1; off < 1024; off <<= 1) {
        int u = (t >= off) ? s[t - off] : 0;
        __syncthreads();
        s[t] += u;
        __syncthreads();
    }
    if (i < n) row_ptr[i] = bpre[b] + s[t] - c;
    if (b == 0 && t == 0) row_ptr[n] = N_EDGES;
}

__global__ __launch_bounds__(256) void scatter_kernel(const int* __restrict__ src,
                                                      const int* __restrict__ dst,
                                                      const int* __restrict__ row_ptr,
                                                      int* __restrict__ cursor,
                                                      int* __restrict__ sorted_src, int n) {
    int i = blockIdx.x * blockDim.x + threadIdx.x;
    if (i < n) {
        int d = dst[i];
        int p = atomicAdd(&cursor[d], 1);
        sorted_src[row_ptr[d] + p] = src[i];
    }
}

// ---------------- splits ----------------

// W -> o-major bf16 hi/lo planes: whi[o][k] for k-concat(Wl,Wr)
__global__ __launch_bounds__(256) void split_w(const float* __restrict__ Wl,
                                               const float* __restrict__ Wr,
                                               unsigned short* __restrict__ whi,
                                               unsigned short* __restrict__ wlo) {
    int i = blockIdx.x * 256 + threadIdx.x;          // 128 o x 256 k
    if (i >= 128 * 256) return;
    int o = i >> 8, k = i & 255;
    float v = (k < 128) ? Wl[o * 128 + k] : Wr[o * 128 + (k - 128)];
    unsigned int hb = bf16_rne_hi(v);
    whi[i] = (unsigned short)(hb >> 16);
    wlo[i] = (unsigned short)(bf16_rne_hi(v - __uint_as_float(hb)) >> 16);
}

// x fp32 -> row-major packed hi/lo (for GEMM root side) + fp16 copy (for gathers)
__global__ __launch_bounds__(256) void split_x(const float* __restrict__ x,
                                               unsigned int* __restrict__ Hp,
                                               __half* __restrict__ Hf) {
    int i = blockIdx.x * 256 + threadIdx.x;          // float4 granules
    if (i >= N_NODES * 32) return;
    float4 v = reinterpret_cast<const float4*>(x)[i];
    u32x4 p;
    p.x = pack_hilo(v.x); p.y = pack_hilo(v.y);
    p.z = pack_hilo(v.z); p.w = pack_hilo(v.w);
    *reinterpret_cast<u32x4*>(Hp + (size_t)i * 4) = p;
    __half2* hf2 = reinterpret_cast<__half2*>(Hf + (size_t)i * 4);
    hf2[0] = __floats2half2_rn(v.x, v.y);
    hf2[1] = __floats2half2_rn(v.z, v.w);
}

// ---------------- mean aggregation: one wave per node, fp16 gathers ----------------
// 256 B/row instead of 512 B -> halves the L2-miss gather traffic.

__global__ __launch_bounds__(256) void aggregate_f16(const __half* __restrict__ Hf,
                                                     const int* __restrict__ row_ptr,
                                                     const int* __restrict__ sorted_src,
                                                     unsigned int* __restrict__ Ap) {
    int wid = (blockIdx.x * blockDim.x + threadIdx.x) >> 6;
    int lane = threadIdx.x & 63;
    if (wid >= N_NODES) return;
    int beg = row_ptr[wid], end = row_ptr[wid + 1];
    int deg = end - beg;
    float a0 = 0.f, a1 = 0.f;                        // this lane's 2 dims
    int j = beg;
    for (; j + 7 < end; j += 8) {                    // 8 gathers in flight
        int s0 = sorted_src[j + 0], s1 = sorted_src[j + 1];
        int s2 = sorted_src[j + 2], s3 = sorted_src[j + 3];
        int s4 = sorted_src[j + 4], s5 = sorted_src[j + 5];
        int s6 = sorted_src[j + 6], s7 = sorted_src[j + 7];
        __half2 v0 = *reinterpret_cast<const __half2*>(Hf + (size_t)s0 * D + lane * 2);
        __half2 v1 = *reinterpret_cast<const __half2*>(Hf + (size_t)s1 * D + lane * 2);
        __half2 v2 = *reinterpret_cast<const __half2*>(Hf + (size_t)s2 * D + lane * 2);
        __half2 v3 = *reinterpret_cast<const __half2*>(Hf + (size_t)s3 * D + lane * 2);
        __half2 v4 = *reinterpret_cast<const __half2*>(Hf + (size_t)s4 * D + lane * 2);
        __half2 v5 = *reinterpret_cast<const __half2*>(Hf + (size_t)s5 * D + lane * 2);
        __half2 v6 = *reinterpret_cast<const __half2*>(Hf + (size_t)s6 * D + lane * 2);
        __half2 v7 = *reinterpret_cast<const __half2*>(Hf + (size_t)s7 * D + lane * 2);
        a0 += (__low2float(v0) + __low2float(v1)) + (__low2float(v2) + __low2float(v3))
            + ((__low2float(v4) + __low2float(v5)) + (__low2float(v6) + __low2float(v7)));
        a1 += (__high2float(v0) + __high2float(v1)) + (__high2float(v2) + __high2float(v3))
            + ((__high2float(v4) + __high2float(v5)) + (__high2float(v6) + __high2float(v7)));
    }
    for (; j < end; ++j) {
        int s = sorted_src[j];
        __half2 v = *reinterpret_cast<const __half2*>(Hf + (size_t)s * D + lane * 2);
        a0 += __low2float(v);
        a1 += __high2float(v);
    }
    float inv = 1.0f / (float)max(deg, 1);
    u32x2 o;
    o.x = pack_hilo(a0 * inv);
    o.y = pack_hilo(a1 * inv);
    *reinterpret_cast<u32x2*>(Ap + (size_t)wid * D + lane * 2) = o;
}

// ---------------- MFMA dual GEMM, W staged in LDS (XOR-swizzled) ----------------
// out[i,:] = act( [agg(i)|h(i)] @ W^T + b ); optionally also writes fp16 copy.

__global__ __launch_bounds__(512, 2) void sage_gemm_mfma(
        const unsigned int* __restrict__ Hp,     // packed root features [N][128]
        const unsigned int* __restrict__ Ap,     // packed agg features  [N][128]
        const unsigned short* __restrict__ WHI,  // [128 o][256 k] bf16 hi
        const unsigned short* __restrict__ WLO,  // [128 o][256 k] bf16 lo
        const float* __restrict__ bl,
        void* __restrict__ outp,
        __half* __restrict__ h16,                // fp16 copy out (may be null)
        int relu, int pack_out) {
    __shared__ short WH[32768];   // 64 KB
    __shared__ short WLl[32768];  // 64 KB
    int tid = threadIdx.x;

    for (int i = tid; i < 4096; i += 512) {
        int o = i >> 5, kg = i & 31;
        int sk = (kg * 8) ^ ((o & 7) << 3);
        *reinterpret_cast<bf16x8*>(&WH[o * 256 + sk]) =
            *reinterpret_cast<const bf16x8*>(WHI + o * 256 + kg * 8);
        *reinterpret_cast<bf16x8*>(&WLl[o * 256 + sk]) =
            *reinterpret_cast<const bf16x8*>(WLO + o * 256 + kg * 8);
    }
    __syncthreads();

    int w = tid >> 6, l = tid & 63;
    int lr = l & 15, lg = l >> 4;
    int sw = (lr & 7) << 3;
    int mt0 = blockIdx.x * 256 + w * 32;
    int mt1 = mt0 + 16;
    int r0 = min(mt0 + lr, N_NODES - 1);
    int r1 = min(mt1 + lr, N_NODES - 1);
    const unsigned int* a0A = Ap + (size_t)r0 * D + lg * 8;
    const unsigned int* a0H = Hp + (size_t)r0 * D + lg * 8;
    const unsigned int* a1A = Ap + (size_t)r1 * D + lg * 8;
    const unsigned int* a1H = Hp + (size_t)r1 * D + lg * 8;

    f32x4 acc0[8], acc1[8];
    #pragma unroll
    for (int nt = 0; nt < 8; ++nt) { acc0[nt] = (f32x4)0.f; acc1[nt] = (f32x4)0.f; }

    u32x4 p00 = *reinterpret_cast<const u32x4*>(a0A);
    u32x4 p01 = *reinterpret_cast<const u32x4*>(a0A + 4);
    u32x4 p10 = *reinterpret_cast<const u32x4*>(a1A);
    u32x4 p11 = *reinterpret_cast<const u32x4*>(a1A + 4);

    #pragma unroll
    for (int kk = 0; kk < 8; ++kk) {
        U16x8 h0, l0, h1, l1;
        h0.u.x = (p00.x >> 16) | (p00.y & 0xffff0000u);
        l0.u.x = (p00.x & 0xffffu) | (p00.y << 16);
        h0.u.y = (p00.z >> 16) | (p00.w & 0xffff0000u);
        l0.u.y = (p00.z & 0xffffu) | (p00.w << 16);
        h0.u.z = (p01.x >> 16) | (p01.y & 0xffff0000u);
        l0.u.z = (p01.x & 0xffffu) | (p01.y << 16);
        h0.u.w = (p01.z >> 16) | (p01.w & 0xffff0000u);
        l0.u.w = (p01.z & 0xffffu) | (p01.w << 16);
        h1.u.x = (p10.x >> 16) | (p10.y & 0xffff0000u);
        l1.u.x = (p10.x & 0xffffu) | (p10.y << 16);
        h1.u.y = (p10.z >> 16) | (p10.w & 0xffff0000u);
        l1.u.y = (p10.z & 0xffffu) | (p10.w << 16);
        h1.u.z = (p11.x >> 16) | (p11.y & 0xffff0000u);
        l1.u.z = (p11.x & 0xffffu) | (p11.y << 16);
        h1.u.w = (p11.z >> 16) | (p11.w & 0xffff0000u);
        l1.u.w = (p11.z & 0xffffu) | (p11.w << 16);
        bf16x8 a0h = h0.b, a0l = l0.b, a1h = h1.b, a1l = l1.b;

        if (kk < 7) {
            int kn = kk + 1;
            const unsigned int* s0 = (kn < 4) ? (a0A + kn * 32) : (a0H + (kn - 4) * 32);
            const unsigned int* s1 = (kn < 4) ? (a1A + kn * 32) : (a1H + (kn - 4) * 32);
            p00 = *reinterpret_cast<const u32x4*>(s0);
            p01 = *reinterpret_cast<const u32x4*>(s0 + 4);
            p10 = *reinterpret_cast<const u32x4*>(s1);
            p11 = *reinterpret_cast<const u32x4*>(s1 + 4);
        }

        int ka = (kk * 32 + lg * 8) ^ sw;
        #pragma unroll
        for (int nt = 0; nt < 8; ++nt) {
            int base = nt * 4096 + lr * 256 + ka;
            bf16x8 bh = *reinterpret_cast<const bf16x8*>(WH + base);
            bf16x8 bl_ = *reinterpret_cast<const bf16x8*>(WLl + base);
            acc0[nt] = __builtin_amdgcn_mfma_f32_16x16x32_bf16(a0h, bh, acc0[nt], 0, 0, 0);
            acc0[nt] = __builtin_amdgcn_mfma_f32_16x16x32_bf16(a0l, bh, acc0[nt], 0, 0, 0);
            acc0[nt] = __builtin_amdgcn_mfma_f32_16x16x32_bf16(a0h, bl_, acc0[nt], 0, 0, 0);
            acc1[nt] = __builtin_amdgcn_mfma_f32_16x16x32_bf16(a1h, bh, acc1[nt], 0, 0, 0);
            acc1[nt] = __builtin_amdgcn_mfma_f32_16x16x32_bf16(a1l, bh, acc1[nt], 0, 0, 0);
            acc1[nt] = __builtin_amdgcn_mfma_f32_16x16x32_bf16(a1h, bl_, acc1[nt], 0, 0, 0);
        }
    }

    // epilogue: D layout col=lane&15, row=(lane>>4)*4+reg [m89-verified]
    #pragma unroll
    for (int nt = 0; nt < 8; ++nt) {
        int col = nt * 16 + lr;
        float bv = bl[col];
        #pragma unroll
        for (int ri = 0; ri < 4; ++ri) {
            int n0 = mt0 + lg * 4 + ri;
            if (n0 < N_NODES) {
                float v = acc0[nt][ri] + bv;
                if (relu) v = fmaxf(v, 0.f);
                if (pack_out)
                    ((unsigned int*)outp)[(size_t)n0 * D + col] = pack_hilo(v);
                else
                    ((float*)outp)[(size_t)n0 * D + col] = v;
                if (h16) h16[(size_t)n0 * D + col] = __float2half_rn(v);
            }
            int n1 = mt1 + lg * 4 + ri;
            if (n1 < N_NODES) {
                float v = acc1[nt][ri] + bv;
                if (relu) v = fmaxf(v, 0.f);
                if (pack_out)
                    ((unsigned int*)outp)[(size_t)n1 * D + col] = pack_hilo(v);
                else
                    ((float*)outp)[(size_t)n1 * D + col] = v;
                if (h16) h16[(size_t)n1 * D + col] = __float2half_rn(v);
            }
        }
    }
}

// ---------------- launch ----------------

extern "C" void kernel_launch(void* const* d_in, const int* in_sizes, int n_in,
                              void* d_out, int out_size, void* d_ws, size_t ws_size,
                              hipStream_t stream) {
    const float* x   = (const float*)d_in[0];
    const int*   src = (const int*)d_in[1];
    const int*   dst = (const int*)d_in[2];
    const float* Wl0 = (const float*)d_in[3];
    const float* bl0 = (const float*)d_in[4];
    const float* Wr0 = (const float*)d_in[5];
    const float* Wl1 = (const float*)d_in[6];
    const float* bl1 = (const float*)d_in[7];
    const float* Wr1 = (const float*)d_in[8];
    const float* Wl2 = (const float*)d_in[9];
    const float* bl2 = (const float*)d_in[10];
    const float* Wr2 = (const float*)d_in[11];

    // ws layout (~84.4 MB; R7 confirmed ws_size >= 110 MB)
    int* cnt        = (int*)d_ws;                        // 100032 ints (reused as cursor)
    int* row_ptr    = cnt + 100032;                      // 100001 ints
    int* sorted_src = row_ptr + 100032;                  // 1.6M ints (ends at 7200256 B)
    unsigned short* W0h = (unsigned short*)((char*)d_ws + 7200256);  // 6 x 64 KB planes
    unsigned short* W0l = W0h + 32768;
    unsigned short* W1h = W0l + 32768;
    unsigned short* W1l = W1h + 32768;
    unsigned short* W2h = W1l + 32768;
    unsigned short* W2l = W2h + 32768;
    unsigned int* Ap = (unsigned int*)((char*)d_ws + 7593472);       // packed agg, 51.2 MB
    __half* Hf       = (__half*)((char*)d_ws + 58793472);            // fp16 H copy, 25.6 MB
    int* bsum = (int*)W0h;   // scan temps alias W planes (written later in stream)
    int* bpre = bsum + 128;

    // packed H lives in d_out (row layout matches final fp32 output; layer-2
    // epilogue overwrites per-row in place, cross-block safe)
    unsigned int* Hp = (unsigned int*)d_out;
    float* outf = (float*)d_out;

    const int EB = (N_EDGES + 255) / 256;      // 6250
    const int GB = (N_NODES + 255) / 256;      // 391 (M=256 per block)
    const int AB = (N_NODES * 64 + 255) / 256; // 25000 (one wave per node)
    const int SB = (N_NODES * 32 + 255) / 256; // 12500 (split_x)
    const int WB = (128 * 256 + 255) / 256;    // 128

    // CSR build (reused by all 3 layers)
    hipMemsetAsync(cnt, 0, N_NODES * sizeof(int), stream);
    hist_kernel<<<EB, 256, 0, stream>>>(dst, cnt, N_EDGES);
    scan_reduce<<<NBS, 256, 0, stream>>>(cnt, bsum, N_NODES);
    scan_partials<<<1, 128, 0, stream>>>(bsum, bpre);
    scan_write<<<NBS, 1024, 0, stream>>>(cnt, bpre, row_ptr, N_NODES);
    hipMemsetAsync(cnt, 0, N_NODES * sizeof(int), stream);
    scatter_kernel<<<EB, 256, 0, stream>>>(src, dst, row_ptr, cnt, sorted_src, N_EDGES);

    // precision splits
    split_x<<<SB, 256, 0, stream>>>(x, Hp, Hf);
    split_w<<<WB, 256, 0, stream>>>(Wl0, Wr0, W0h, W0l);
    split_w<<<WB, 256, 0, stream>>>(Wl1, Wr1, W1h, W1l);
    split_w<<<WB, 256, 0, stream>>>(Wl2, Wr2, W2h, W2l);

    // layer 0: Hp(x) -> Hp (ReLU, packed) + Hf (fp16 copy for next gather)
    aggregate_f16<<<AB, 256, 0, stream>>>(Hf, row_ptr, sorted_src, Ap);
    sage_gemm_mfma<<<GB, 512, 0, stream>>>(Hp, Ap, W0h, W0l, bl0, Hp, Hf, 1, 1);
    // layer 1
    aggregate_f16<<<AB, 256, 0, stream>>>(Hf, row_ptr, sorted_src, Ap);
    sage_gemm_mfma<<<GB, 512, 0, stream>>>(Hp, Ap, W1h, W1l, bl1, Hp, Hf, 1, 1);
    // layer 2: final fp32 into d_out (in-place per-row over Hp), no fp16 copy
    aggregate_f16<<<AB, 256, 0, stream>>>(Hf, row_ptr, sorted_src, Ap);
    sage_gemm_mfma<<<GB, 512, 0, stream>>>(Hp, Ap, W2h, W2l, bl2, outf, (__half*)nullptr, 0, 0);
}